// Round 8
// baseline (4138.754 us; speedup 1.0000x reference)
//
#include <hip/hip_runtime.h>
#include <hip/hip_bf16.h>

// GRU last-hidden: B=64, T=512, I=256, H=512, fp32 in/out.
//
// Round-13: XCD-local exchange with CORRECT codegen. R12 post-mortem:
// VGPR_Count=128 proved the array-parameter refactor spilled the weight
// fragments to scratch (rule: arrays passed as function params become
// addressable memory) - the round tested scratch speed, not the medium.
// This round:
//  * SINGLE-BODY kernel (R5/R11-proven codegen): weights as plain locals,
//    runtime-uniform `fast` flag selecting two macro-expanded T-loops.
//    __launch_bounds__(256,2) -> VGPR cap 256 >= ~240 needed.
//  * Workers = bid%8==0 of a 512-block exact-fill launch (round-robin
//    block->XCD mapping, same evidence base as the XCD swizzle). Workers
//    do the ENTIRE prologue themselves (~100us once); non-workers return
//    at instruction 1. Zero dependency on non-worker blocks anywhere.
//  * Replay-safe timestamp barriers (s_memrealtime >= kernel-entry t0;
//    stale ws content always older). 2-round coherence self-test with
//    epoch-tagged magic: arm own L1/L2 -> peer plain-store + drain (dirty
//    in peer's L2 only, never L3) -> buffer_inv sc0 + plain re-read.
//    One shared L2 + working L1-invalidate <=> all 64 fresh magics.
//    Any mismatch -> collective PRE-LOOP demote to R5-proven sc1/L3
//    protocol (mode uniform across workers; mixed-mode impossible).
//  * T-loop = UNCHANGED R5 protocol; fast swaps sc1->plain (XCD-L2
//    medium) + buffer_inv sc0 before tag polls (L1 staleness fix).

#define NB 64
#define NT 512
#define NI 256
#define NH 512

// ws layout (all gating timestamp-based; no zeroed-ws assumptions):
#define OFF_TSB    0u        // 8 barrier arrays x 4KB = [0,32K)
#define OFF_DEMOTE 32768u    // u64 timestamp marker
#define OFF_TESTA  36864u    // 64 test slots x 64B
#define OFF_TAGS   40960u    // int[4][64]
#define OFF_HB0    65536u    // 64KB h buffer (parity 0)
#define OFF_HB1    131072u   // 64KB h buffer (parity 1)
#define OFF_XB     262144u   // x as bf16 [b][t][i], 16MB

typedef __attribute__((ext_vector_type(8))) short bf16x8;
typedef __attribute__((ext_vector_type(4))) float f32x4;
typedef __attribute__((ext_vector_type(4))) int i32x4;

static __device__ __forceinline__ short f2b(float f) {
  unsigned u = __builtin_bit_cast(unsigned, f);
  unsigned r = (u + 0x7fffu + ((u >> 16) & 1u)) >> 16;
  return (short)r;
}
static __device__ __forceinline__ float sigm(float x) {
  return 1.0f / (1.0f + __expf(-x));
}
static __device__ __forceinline__ float tanh_f(float x) {
  return 1.0f - 2.0f / (__expf(2.0f * x) + 1.0f);
}

// Replay-safe timestamp barrier among the 64 workers. idx selects a
// dedicated slot array (never reused within a launch). RELEASE store
// flushes this worker's dirty L2 lines; trailing threadfence invalidates
// so post-barrier reads are fresh either mode.
static __device__ __forceinline__ void tsbar(unsigned char* ws, int idx,
                                             int rank, int tid, int wave,
                                             int lane,
                                             unsigned long long t0) {
  unsigned long long* base =
      (unsigned long long*)(ws + OFF_TSB + (unsigned)idx * 4096u);
  __syncthreads();
  if (tid == 0)
    __hip_atomic_store(&base[rank * 8], __builtin_amdgcn_s_memrealtime(),
                       __ATOMIC_RELEASE, __HIP_MEMORY_SCOPE_AGENT);
  if (wave == 0) {
    while (__hip_atomic_load(&base[lane * 8], __ATOMIC_RELAXED,
                             __HIP_MEMORY_SCOPE_AGENT) < t0)
      __builtin_amdgcn_s_sleep(1);
  }
  __syncthreads();
  __threadfence();
}

// The R5-proven recurrence loop; LDSUF/STSUF = "" (fast: plain ops through
// the shared XCD L2) or " sc1" (classic: agent-coherent via L3). FASTINV
// adds buffer_inv sc0 (L1 invalidate) before each tag poll / at t=0.
#define TLOOP(LDSUF, STSUF, FASTINV)                                          \
  for (int t = 0; t < NT; t++) {                                              \
    const unsigned short* hcur = (t & 1) ? hb1 : hb0;                         \
    unsigned short* hnext      = (t & 1) ? hb0 : hb1;                         \
    f32x4 aX0 = {0.f,0.f,0.f,0.f}, aX1 = {0.f,0.f,0.f,0.f};                   \
    f32x4 aH0 = {0.f,0.f,0.f,0.f}, aH1 = {0.f,0.f,0.f,0.f};                   \
    const bf16x8* xr = (const bf16x8*)(xb + ((size_t)b0 * NT + t) * NI);      \
    _Pragma("unroll") for (int kk = 0; kk < 8; kk++) {                        \
      bf16x8 a = xr[kk * 4 + q];                                              \
      aX0 = __builtin_amdgcn_mfma_f32_16x16x32_bf16(a, wi[0][kk], aX0,0,0,0); \
      aX1 = __builtin_amdgcn_mfma_f32_16x16x32_bf16(a, wi[1][kk], aX1,0,0,0); \
    }                                                                         \
    if (t > 0) {                                                              \
      const int need = t + 1;                                                 \
      for (;;) {                                                              \
        if (FASTINV) asm volatile("buffer_inv sc0" ::: "memory");             \
        int v;                                                                \
        asm volatile("global_load_dword %0, %1, off" LDSUF                    \
                     : "=v"(v) : "v"(tagp));                                  \
        asm volatile("s_waitcnt vmcnt(0)" : "+v"(v) :: "memory");             \
        if (__all(v >= need)) break;                                          \
      }                                                                       \
    } else if (FASTINV) {                                                     \
      asm volatile("buffer_inv sc0" ::: "memory");                            \
    }                                                                         \
    i32x4 hv[16];                                                             \
    _Pragma("unroll") for (int kk2 = 0; kk2 < 16; kk2++) {                    \
      const void* ap_ =                                                       \
          (const char*)hcur + (size_t)(((kk2 * 4 + q) * 64 + b0) << 4);       \
      asm volatile("global_load_dwordx4 %0, %1, off" LDSUF                    \
                   : "=v"(hv[kk2]) : "v"(ap_));                               \
    }                                                                         \
    asm volatile("s_waitcnt vmcnt(0)"                                         \
                 : "+v"(hv[0]), "+v"(hv[1]), "+v"(hv[2]), "+v"(hv[3]),        \
                   "+v"(hv[4]), "+v"(hv[5]), "+v"(hv[6]), "+v"(hv[7]),        \
                   "+v"(hv[8]), "+v"(hv[9]), "+v"(hv[10]), "+v"(hv[11]),      \
                   "+v"(hv[12]), "+v"(hv[13]), "+v"(hv[14]), "+v"(hv[15])     \
                 ::"memory");                                                 \
    _Pragma("unroll") for (int kk = 0; kk < 16; kk++) {                       \
      bf16x8 a = __builtin_bit_cast(bf16x8, hv[kk]);                          \
      aH0 = __builtin_amdgcn_mfma_f32_16x16x32_bf16(a, wh[0][kk], aH0,0,0,0); \
      aH1 = __builtin_amdgcn_mfma_f32_16x16x32_bf16(a, wh[1][kk], aH1,0,0,0); \
    }                                                                         \
    _Pragma("unroll") for (int r = 0; r < 4; r++) {                           \
      float xz = __shfl_xor(aX0[r], 8, 64);                                   \
      float hz = __shfl_xor(aH0[r], 8, 64);                                   \
      float rr = sigm(aX0[r] + bri + aH0[r] + brh);                           \
      float zz = sigm(xz + bzi + hz + bzh);                                   \
      float nn = tanh_f(aX1[r] + bni + rr * (aH1[r] + bnh));                  \
      float hv2 = (1.0f - zz) * nn + zz * hold[r];                            \
      hold[r] = hv2;                                                          \
      if (c < 8) trans[wave][q * 4 + r][c] = (unsigned short)f2b(hv2);        \
    }                                                                         \
    if (t < NT - 1) {                                                         \
      asm volatile("s_waitcnt lgkmcnt(0)" ::: "memory");                      \
      if (lane < 16) {                                                        \
        int b = wave * 16 + lane;                                             \
        i32x4 pk = *(const i32x4*)&trans[wave][lane][0];                      \
        void* dst = (char*)hnext + ((size_t)(wg * 64 + b) << 4);              \
        asm volatile("global_store_dwordx4 %0, %1, off" STSUF                 \
                     :: "v"(dst), "v"(pk) : "memory");                        \
      }                                                                       \
      asm volatile("s_waitcnt vmcnt(0)" ::: "memory");                        \
      if (lane == 0) {                                                        \
        int* tp = &mytags[wg];                                                \
        int tv = t + 2;                                                       \
        asm volatile("global_store_dword %0, %1, off" STSUF                   \
                     :: "v"(tp), "v"(tv) : "memory");                         \
      }                                                                       \
    }                                                                         \
  }

__global__ __launch_bounds__(256, 2)
void gru_persistent(const float* __restrict__ x,
                    const float* __restrict__ Wih,
                    const float* __restrict__ Whh,
                    const float* __restrict__ bih,
                    const float* __restrict__ bhh,
                    float* __restrict__ out,
                    unsigned char* __restrict__ ws) {
  const int bid = blockIdx.x;          // 0..511
  if (bid & 7) return;                 // non-worker: free the slot instantly
  const int wg  = bid >> 3;            // worker rank 0..63 (one per XCD-slot
                                       // group; all on XCD0 if round-robin)
  const int tid  = threadIdx.x;
  const int wave = tid >> 6;
  const int lane = tid & 63;
  const int c    = lane & 15;
  const int q    = lane >> 4;

  const unsigned long long t0 = __builtin_amdgcn_s_memrealtime();

  int* tags = (int*)(ws + OFF_TAGS);
  unsigned short* hb0 = (unsigned short*)(ws + OFF_HB0);
  unsigned short* hb1 = (unsigned short*)(ws + OFF_HB1);
  unsigned short* xb  = (unsigned short*)(ws + OFF_XB);

  __shared__ __align__(16) unsigned short trans[4][16][8];
  __shared__ int s_bad;

  // ---- prologue (workers only, split 64 ways): x fp32->bf16, h0, tags --
  {
    const float4* x4 = (const float4*)x;
    const int total4 = NB * NT * NI / 4;
    const int nthr = 64 * 256;
    for (int i = wg * 256 + tid; i < total4; i += nthr) {
      float4 v = x4[i];
      ushort4 o;
      o.x = (unsigned short)f2b(v.x);
      o.y = (unsigned short)f2b(v.y);
      o.z = (unsigned short)f2b(v.z);
      o.w = (unsigned short)f2b(v.w);
      ((ushort4*)xb)[i] = o;
    }
    ((unsigned*)hb0)[wg * 256 + tid] = 0u;  // h0 = 0 (64KB total)
    if (wg == 0) tags[tid] = 0;             // 256 tags
  }

  // ---- loop-invariant weight fragments (plain locals - R5 codegen) ----
  bf16x8 wh[2][16];
  bf16x8 wi[2][8];
#pragma unroll
  for (int nt = 0; nt < 2; nt++) {
    int nl = nt * 16 + c;
    bool valid = nl < 24;
    int gate = nl >> 3;
    int jj = nl & 7;
    int grow = valid ? (gate * NH + wg * 8 + jj) : 0;
#pragma unroll
    for (int kk = 0; kk < 16; kk++) {
      const float* p = Whh + (size_t)grow * NH + kk * 32 + q * 8;
      bf16x8 f;
#pragma unroll
      for (int e = 0; e < 8; e++) f[e] = valid ? f2b(p[e]) : (short)0;
      wh[nt][kk] = f;
    }
#pragma unroll
    for (int kk = 0; kk < 8; kk++) {
      const float* p = Wih + (size_t)grow * NI + kk * 32 + q * 8;
      bf16x8 f;
#pragma unroll
      for (int e = 0; e < 8; e++) f[e] = valid ? f2b(p[e]) : (short)0;
      wi[nt][kk] = f;
    }
  }

  const int jcol = wg * 8 + (c & 7);
  const float bri = bih[jcol],          brh = bhh[jcol];
  const float bzi = bih[NH + jcol],     bzh = bhh[NH + jcol];
  const float bni = bih[2 * NH + jcol], bnh = bhh[2 * NH + jcol];

  float hold[4] = {0.f, 0.f, 0.f, 0.f};

  // ---- barrier 0: all workers' prologue flushed & visible ----
  tsbar(ws, 0, wg, tid, wave, lane, t0);

  // ---- coherence self-test, 2 rounds (epoch-tagged; replay-immune) ----
  if (tid == 0) s_bad = 0;
  __syncthreads();
#pragma unroll 1
  for (int rnd = 0; rnd < 2; rnd++) {
    // phase 1: arm this CU's L1/L2 with the 64 test lines
    if (wave == 0) {
      int v;
      const void* p = ws + OFF_TESTA + (size_t)lane * 64;
      asm volatile("global_load_dword %0, %1, off" : "=v"(v) : "v"(p));
      asm volatile("s_waitcnt vmcnt(0)" : "+v"(v)::"memory");
    }
    tsbar(ws, 1 + rnd * 3, wg, tid, wave, lane, t0);
    // per-round epoch = rank-0's barrier timestamp (fresh, shared)
    const unsigned ep = (unsigned)__hip_atomic_load(
        (const unsigned long long*)(ws + OFF_TSB + (1 + rnd * 3) * 4096u),
        __ATOMIC_RELAXED, __HIP_MEMORY_SCOPE_AGENT);
    // phase 2: plain-store epoch-tagged magic + drain (own L2 only;
    // deliberately NEVER written back to L3 in this window)
    if (tid == 0) {
      unsigned mg = (ep ^ 0x5EEDBEEFu) + (unsigned)wg * 2654435761u;
      void* p = ws + OFF_TESTA + (size_t)wg * 64;
      asm volatile("global_store_dword %0, %1, off" :: "v"(p), "v"(mg)
                   : "memory");
      asm volatile("s_waitcnt vmcnt(0)" ::: "memory");
    }
    tsbar(ws, 2 + rnd * 3, wg, tid, wave, lane, t0);
    // phase 3: inv L1 + plain re-read all 64; any non-fresh -> demote
    {
      int bad = 0;
      if (wave == 0) {
        asm volatile("buffer_inv sc0" ::: "memory");
        int v;
        const void* p = ws + OFF_TESTA + (size_t)lane * 64;
        asm volatile("global_load_dword %0, %1, off" : "=v"(v) : "v"(p));
        asm volatile("s_waitcnt vmcnt(0)" : "+v"(v)::"memory");
        unsigned want = (ep ^ 0x5EEDBEEFu) + (unsigned)lane * 2654435761u;
        bad = (v != (int)want);
      }
      if (bad) s_bad = 1;
      __syncthreads();
      if (s_bad && tid == 0)
        __hip_atomic_store((unsigned long long*)(ws + OFF_DEMOTE),
                           __builtin_amdgcn_s_memrealtime(),
                           __ATOMIC_RELEASE, __HIP_MEMORY_SCOPE_AGENT);
      __syncthreads();
    }
    tsbar(ws, 3 + rnd * 3, wg, tid, wave, lane, t0);
  }
  const bool fast =
      __hip_atomic_load((const unsigned long long*)(ws + OFF_DEMOTE),
                        __ATOMIC_RELAXED, __HIP_MEMORY_SCOPE_AGENT) < t0;

  const int b0 = wave * 16 + c;
  int* mytags = tags + wave * 64;
  const int* tagp = mytags + lane;

  if (fast) {
    TLOOP("", "", 1)
  } else {
    TLOOP(" sc1", " sc1", 0)
  }

  // final h (fp32 master copy) -> d_out
  if (c < 8) {
#pragma unroll
    for (int r = 0; r < 4; r++) {
      int b = wave * 16 + q * 4 + r;
      out[(size_t)b * NH + wg * 8 + c] = hold[r];
    }
  }
}

extern "C" void kernel_launch(void* const* d_in, const int* in_sizes, int n_in,
                              void* d_out, int out_size, void* d_ws, size_t ws_size,
                              hipStream_t stream) {
  const float* x   = (const float*)d_in[0];
  const float* Wih = (const float*)d_in[1];
  const float* Whh = (const float*)d_in[2];
  const float* bih = (const float*)d_in[3];
  const float* bhh = (const float*)d_in[4];
  float* out = (float*)d_out;
  hipLaunchKernelGGL(gru_persistent, dim3(512), dim3(256), 0, stream,
                     x, Wih, Whh, bih, bhh, out, (unsigned char*)d_ws);
}

// Round 9
// 1916.547 us; speedup vs baseline: 2.1595x; 2.1595x over previous
//
#include <hip/hip_runtime.h>
#include <hip/hip_bf16.h>

// GRU last-hidden: B=64, T=512, I=256, H=512, fp32 in/out.
// Persistent kernel: 64 WGs x 256 thr. WG w owns h-cols [8w,8w+8) for ALL
// batches; weights live in VGPR MFMA B-fragments for the whole kernel.
//
// Round-14: DE-COLLIDE the all-to-all on the proven R5 base (1834us).
// Theory: R6 (+2x volume -> +1.2us/step) + R7/R8 (latency protocols
// neutral) => the exchange is L3 SAME-LINE CONTENTION-bound: all 64 WGs
// read the identical 64KB h buffer in the identical fragment order, so
// every 64B line gets ~64 near-simultaneous sc1 requests (and every tag
// line ~64 polling requests per spin). Changes, protocol untouched:
//  1) 8-way ROTATED h-load issue order: WG w starts its 16-load burst at
//     fragment 2*(w&7). Compile-time rotation (8 uniform branches) keeps
//     hv[]/wh[] statically indexed (no scratch). Same addresses, same
//     single vmcnt(0) -> semantics identical; simultaneous same-line
//     readers drop 64 -> 8.
//  2) 4x REPLICATED tags: producer fires 4 tag stores (after the existing
//     data drain, fire-and-forget); consumer WG w polls replica w&3.
//     Poll same-line collisions drop 64 -> 16.
//  3) Replay-safe timestamp init barrier (proven R11/R13) replaces the
//     slots barrier (removes the stale-tag race on graph replays).
// Codegen guard: launch_bounds(256,1) — R12/R13 proved (256,2) halves the
// unified VGPR/AGPR budget to 128+128 and spills the weight set.

#define NB 64
#define NT 512
#define NI 256
#define NH 512

typedef __attribute__((ext_vector_type(8))) short bf16x8;
typedef __attribute__((ext_vector_type(4))) float f32x4;
typedef __attribute__((ext_vector_type(4))) int i32x4;

static __device__ __forceinline__ short f2b(float f) {
  unsigned u = __builtin_bit_cast(unsigned, f);
  unsigned r = (u + 0x7fffu + ((u >> 16) & 1u)) >> 16;
  return (short)r;
}
static __device__ __forceinline__ float sigm(float x) {
  return 1.0f / (1.0f + __expf(-x));
}
static __device__ __forceinline__ float tanh_f(float x) {
  return 1.0f - 2.0f / (__expf(2.0f * x) + 1.0f);
}

// Issue the 16 h-fragment loads in rotated order, starting at fragment R
// (compile-time literal). kk2 folds to a constant per unrolled i, so
// hv[kk2] stays register-allocated (rule: no runtime-indexed vectors).
#define ISSUE16(R)                                                            \
  do {                                                                        \
    _Pragma("unroll") for (int i_ = 0; i_ < 16; i_++) {                       \
      const int kk2 = (i_ + (R)) & 15;                                        \
      const void* ap_ =                                                       \
          (const char*)hcur + (size_t)(((kk2 * 4 + q) * 64 + b0) << 4);       \
      asm volatile("global_load_dwordx4 %0, %1, off sc1"                      \
                   : "=v"(hv[kk2]) : "v"(ap_));                               \
    }                                                                         \
  } while (0)

__global__ __launch_bounds__(256, 1)
void gru_persistent(const float* __restrict__ x,
                    const float* __restrict__ Wih,
                    const float* __restrict__ Whh,
                    const float* __restrict__ bih,
                    const float* __restrict__ bhh,
                    float* __restrict__ out,
                    unsigned char* __restrict__ ws) {
  const int wg   = blockIdx.x;    // 0..63 : owns h-cols [8wg, 8wg+8)
  const int tid  = threadIdx.x;   // 0..255
  const int wave = tid >> 6;      // 0..3  : owns batches [16*wave, +16)
  const int lane = tid & 63;
  const int c    = lane & 15;     // tile col / A-row index
  const int q    = lane >> 4;     // quad: k-group (A/B), row-group (C/D)

  const unsigned long long t0 = __builtin_amdgcn_s_memrealtime();

  // ws layout: flags u64[64] stride 64B @0; tags int[4 replicas][4][64]
  // @8K (4KB); hb0 @16K (64KB); hb1 @16K+64K; xb (x as bf16 [b][t][i])
  // @16K+128K (16MB).
  unsigned long long* flags = (unsigned long long*)ws;
  int* tags = (int*)(ws + 8192);
  unsigned short* hb0 = (unsigned short*)(ws + 16384);
  unsigned short* hb1 = (unsigned short*)(ws + 16384 + 65536);
  unsigned short* xb  = (unsigned short*)(ws + 16384 + 2 * 65536);

  __shared__ __align__(16) unsigned short trans[4][16][8];  // per-wave bounce

  // ---- prologue: x fp32->bf16, zero h0 and all tag replicas ----
  {
    const float4* x4 = (const float4*)x;
    const int total4 = NB * NT * NI / 4;
    const int nthr = NB * 256;
    for (int i = wg * 256 + tid; i < total4; i += nthr) {
      float4 v = x4[i];
      ushort4 o;
      o.x = (unsigned short)f2b(v.x);
      o.y = (unsigned short)f2b(v.y);
      o.z = (unsigned short)f2b(v.z);
      o.w = (unsigned short)f2b(v.w);
      ((ushort4*)xb)[i] = o;
    }
    ((unsigned int*)hb0)[wg * 256 + tid] = 0u;  // h0 = 0 (64KB total)
    if (wg == 0) {
#pragma unroll
      for (int r2 = 0; r2 < 4; r2++) tags[r2 * 256 + tid] = 0;  // 1024 tags
    }
  }

  // ---- loop-invariant weight fragments into registers ----
  bf16x8 wh[2][16];  // W_hh, K=512 -> 16 k-steps
  bf16x8 wi[2][8];   // W_ih, K=256 -> 8 k-steps
#pragma unroll
  for (int nt = 0; nt < 2; nt++) {
    int nl = nt * 16 + c;
    bool valid = nl < 24;
    int gate = nl >> 3;
    int jj = nl & 7;
    int grow = valid ? (gate * NH + wg * 8 + jj) : 0;
#pragma unroll
    for (int kk = 0; kk < 16; kk++) {
      const float* p = Whh + (size_t)grow * NH + kk * 32 + q * 8;
      bf16x8 f;
#pragma unroll
      for (int e = 0; e < 8; e++) f[e] = valid ? f2b(p[e]) : (short)0;
      wh[nt][kk] = f;
    }
#pragma unroll
    for (int kk = 0; kk < 8; kk++) {
      const float* p = Wih + (size_t)grow * NI + kk * 32 + q * 8;
      bf16x8 f;
#pragma unroll
      for (int e = 0; e < 8; e++) f[e] = valid ? f2b(p[e]) : (short)0;
      wi[nt][kk] = f;
    }
  }

  const int jcol = wg * 8 + (c & 7);
  const float bri = bih[jcol],          brh = bhh[jcol];
  const float bzi = bih[NH + jcol],     bzh = bhh[NH + jcol];
  const float bni = bih[2 * NH + jcol], bnh = bhh[2 * NH + jcol];

  float hold[4] = {0.f, 0.f, 0.f, 0.f};  // fp32 master state (c<8 lanes)

  // ---- replay-safe timestamp init barrier (R11/R13-proven): flag =
  // post-prologue realtime (RELEASE flushes prologue writes); readers
  // pass only on flag >= own entry time -> stale ws always blocks ----
  __syncthreads();
  if (tid == 0)
    __hip_atomic_store(&flags[wg * 8], __builtin_amdgcn_s_memrealtime(),
                       __ATOMIC_RELEASE, __HIP_MEMORY_SCOPE_AGENT);
  if (wave == 0) {
    while (__hip_atomic_load(&flags[lane * 8], __ATOMIC_RELAXED,
                             __HIP_MEMORY_SCOPE_AGENT) < t0)
      __builtin_amdgcn_s_sleep(1);
  }
  __syncthreads();
  __threadfence();

  const int b0 = wave * 16 + c;       // A-fragment batch row for this lane
  const int rot = wg & 7;             // rotation phase (uniform per WG)
  // consumer polls replica wg&3 for its wave-plane
  const int* tagp = tags + (wg & 3) * 256 + wave * 64 + lane;

  for (int t = 0; t < NT; t++) {
    const unsigned short* hcur = (t & 1) ? hb1 : hb0;
    unsigned short* hnext      = (t & 1) ? hb0 : hb1;

    f32x4 aX0 = {0.f, 0.f, 0.f, 0.f}, aX1 = {0.f, 0.f, 0.f, 0.f};
    f32x4 aH0 = {0.f, 0.f, 0.f, 0.f}, aH1 = {0.f, 0.f, 0.f, 0.f};

    const bf16x8* xr = (const bf16x8*)(xb + ((size_t)b0 * NT + t) * NI);

    // x-projection (cached loads; fills the wall-clock while producers
    // publish). Fully before the poll.
#pragma unroll
    for (int kk = 0; kk < 8; kk++) {
      bf16x8 a = xr[kk * 4 + q];
      aX0 = __builtin_amdgcn_mfma_f32_16x16x32_bf16(a, wi[0][kk], aX0, 0, 0, 0);
      aX1 = __builtin_amdgcn_mfma_f32_16x16x32_bf16(a, wi[1][kk], aX1, 0, 0, 0);
    }

    // poll for h_t from this wave-plane's 64 producers (replica wg&3):
    // one coalesced agent-coherent dword load per iteration.
    if (t > 0) {
      const int need = t + 1;
      for (;;) {
        int v;
        asm volatile("global_load_dword %0, %1, off sc1"
                     : "=v"(v) : "v"(tagp));
        asm volatile("s_waitcnt vmcnt(0)" : "+v"(v)::"memory");
        if (__all(v >= need)) break;
      }
    }

    // h fragment burst: 16 coalesced 16B sc1 loads, issue order ROTATED
    // by 2*(wg&7) to spread same-line requests across the step's load
    // window (compile-time rotation -> static register indexing).
    i32x4 hv[16];
    if      (rot == 0) ISSUE16(0);
    else if (rot == 1) ISSUE16(2);
    else if (rot == 2) ISSUE16(4);
    else if (rot == 3) ISSUE16(6);
    else if (rot == 4) ISSUE16(8);
    else if (rot == 5) ISSUE16(10);
    else if (rot == 6) ISSUE16(12);
    else               ISSUE16(14);
    asm volatile("s_waitcnt vmcnt(0)"
                 : "+v"(hv[0]), "+v"(hv[1]), "+v"(hv[2]), "+v"(hv[3]),
                   "+v"(hv[4]), "+v"(hv[5]), "+v"(hv[6]), "+v"(hv[7]),
                   "+v"(hv[8]), "+v"(hv[9]), "+v"(hv[10]), "+v"(hv[11]),
                   "+v"(hv[12]), "+v"(hv[13]), "+v"(hv[14]), "+v"(hv[15])
                 ::"memory");

    // h-projection
#pragma unroll
    for (int kk = 0; kk < 16; kk++) {
      bf16x8 a = __builtin_bit_cast(bf16x8, hv[kk]);
      aH0 = __builtin_amdgcn_mfma_f32_16x16x32_bf16(a, wh[0][kk], aH0, 0, 0, 0);
      aH1 = __builtin_amdgcn_mfma_f32_16x16x32_bf16(a, wh[1][kk], aH1, 0, 0, 0);
    }

    // epilogue: C/D layout col=lane&15, row=q*4+reg. Lane c<8 owns col wg*8+c.
#pragma unroll
    for (int r = 0; r < 4; r++) {
      float xz = __shfl_xor(aX0[r], 8, 64);
      float hz = __shfl_xor(aH0[r], 8, 64);
      float rr = sigm(aX0[r] + bri + aH0[r] + brh);
      float zz = sigm(xz + bzi + hz + bzh);
      float nn = tanh_f(aX1[r] + bni + rr * (aH1[r] + bnh));
      float hv2 = (1.0f - zz) * nn + zz * hold[r];
      hold[r] = hv2;
      if (c < 8) trans[wave][q * 4 + r][c] = (unsigned short)f2b(hv2);
    }

    if (t < NT - 1) {
      // per-wave LDS transpose -> coalesced 16B data stores (sc1), drain,
      // then 4 replicated tag stores (fire-and-forget; monotone values;
      // data-before-flag preserved by the drain, exactly as R5).
      asm volatile("s_waitcnt lgkmcnt(0)" ::: "memory");
      if (lane < 16) {
        int b = wave * 16 + lane;
        i32x4 pk = *(const i32x4*)&trans[wave][lane][0];
        void* dst = (char*)hnext + ((size_t)(wg * 64 + b) << 4);
        asm volatile("global_store_dwordx4 %0, %1, off sc1"
                     :: "v"(dst), "v"(pk) : "memory");
      }
      asm volatile("s_waitcnt vmcnt(0)" ::: "memory");
      if (lane == 0) {
#pragma unroll
        for (int r2 = 0; r2 < 4; r2++)
          __hip_atomic_store(&tags[r2 * 256 + wave * 64 + wg], t + 2,
                             __ATOMIC_RELAXED, __HIP_MEMORY_SCOPE_AGENT);
      }
    }
  }

  // final h (fp32 master copy) -> d_out
  if (c < 8) {
#pragma unroll
    for (int r = 0; r < 4; r++) {
      int b = wave * 16 + q * 4 + r;
      out[(size_t)b * NH + wg * 8 + c] = hold[r];
    }
  }
}

extern "C" void kernel_launch(void* const* d_in, const int* in_sizes, int n_in,
                              void* d_out, int out_size, void* d_ws, size_t ws_size,
                              hipStream_t stream) {
  const float* x   = (const float*)d_in[0];
  const float* Wih = (const float*)d_in[1];
  const float* Whh = (const float*)d_in[2];
  const float* bih = (const float*)d_in[3];
  const float* bhh = (const float*)d_in[4];
  float* out = (float*)d_out;
  hipLaunchKernelGGL(gru_persistent, dim3(NB), dim3(256), 0, stream,
                     x, Wih, Whh, bih, bhh, out, (unsigned char*)d_ws);
}